// Round 1
// baseline (124.887 us; speedup 1.0000x reference)
//
#include <hip/hip_runtime.h>
#include <math.h>

// Adder2D: out[n,co,h,w] = -sum_{ci,kh,kw} |x[n,ci,h+kh-1,w+kw-1] - w[co,ci,kh,kw]|
// x: [16,64,32,32] f32, w: [64,64,3,3] f32, out: [16,64,32,32] f32, pad=1 stride=1.
//
// VALU-bound problem (604M sub+abs+acc element-ops, no MFMA path for L1 dist).
// Block = 256 thr = 8 rows x 32 cols, 1 pixel/thread, CG=4 co accumulators.
// Grid = 4 rowgroups x 16 cogroups x 16 n = 1024 blocks -> 4 blocks/CU.
// x staged in LDS in 8-ci chunks with halo+zero-pad; w indexed block-uniformly
// (compiler scalarizes to s_load -> SMEM pipe, off the VALU critical path).

#define N_   16
#define CI_  64
#define CO_  64
#define HW_  32
#define K_   3
#define CG   4    // co per block
#define RG   8    // output rows per block
#define CIC  8    // ci planes staged per barrier round

__global__ __launch_bounds__(256, 4) void adder2d_kernel(
    const float* __restrict__ x, const float* __restrict__ w,
    float* __restrict__ out)
{
    __shared__ float xs[CIC][RG + 2][HW_ + 2];   // 8*10*34*4 = 10880 B

    const int tid = threadIdx.x;
    const int c   = tid & 31;        // output col
    const int rl  = tid >> 5;        // local row 0..7
    const int r0  = blockIdx.x * RG;
    const int co0 = blockIdx.y * CG;
    const int n   = blockIdx.z;
    const int r   = r0 + rl;

    float acc[CG];
#pragma unroll
    for (int j = 0; j < CG; ++j) acc[j] = 0.f;

    const float* xn = x + (size_t)n * CI_ * HW_ * HW_;

    for (int cc0 = 0; cc0 < CI_; cc0 += CIC) {
        __syncthreads();   // protect LDS from previous round's readers
        // stage CIC padded planes: [CIC][RG+2][HW_+2], zeros in the halo OOB
        for (int idx = tid; idx < CIC * (RG + 2) * (HW_ + 2); idx += 256) {
            int cil = idx / ((RG + 2) * (HW_ + 2));
            int rem = idx - cil * ((RG + 2) * (HW_ + 2));
            int rr  = rem / (HW_ + 2);
            int cc  = rem - rr * (HW_ + 2);
            int gr  = r0 - 1 + rr;
            int gc  = cc - 1;
            float v = 0.f;
            if ((unsigned)gr < HW_ && (unsigned)gc < HW_)
                v = xn[(cc0 + cil) * HW_ * HW_ + gr * HW_ + gc];
            ((float*)xs)[idx] = v;
        }
        __syncthreads();

        for (int cil = 0; cil < CIC; ++cil) {
            const int ci = cc0 + cil;

            // block-uniform w fetch -> scalar loads (SMEM pipe)
            float wv[CG][9];
#pragma unroll
            for (int j = 0; j < CG; ++j)
#pragma unroll
                for (int t = 0; t < 9; ++t)
                    wv[j][t] = w[((co0 + j) * CI_ + ci) * 9 + t];

            // 9 LDS reads for this pixel's 3x3 patch (2-way bank alias = free)
            float xv[9];
#pragma unroll
            for (int kh = 0; kh < K_; ++kh)
#pragma unroll
                for (int kw = 0; kw < K_; ++kw)
                    xv[kh * 3 + kw] = xs[cil][rl + kh][c + kw];

            // 72 fused sub + add-with-abs-modifier per ci
#pragma unroll
            for (int j = 0; j < CG; ++j)
#pragma unroll
                for (int t = 0; t < 9; ++t)
                    acc[j] += fabsf(xv[t] - wv[j][t]);
        }
    }

    float* on = out + ((size_t)n * CO_ + co0) * HW_ * HW_ + r * HW_ + c;
#pragma unroll
    for (int j = 0; j < CG; ++j)
        on[j * HW_ * HW_] = -acc[j];
}

extern "C" void kernel_launch(void* const* d_in, const int* in_sizes, int n_in,
                              void* d_out, int out_size, void* d_ws, size_t ws_size,
                              hipStream_t stream) {
    const float* x  = (const float*)d_in[0];
    const float* wp = (const float*)d_in[1];
    float* out      = (float*)d_out;
    dim3 grid(HW_ / RG, CO_ / CG, N_);   // (4, 16, 16) = 1024 blocks
    adder2d_kernel<<<grid, 256, 0, stream>>>(x, wp, out);
}